// Round 3
// baseline (257.883 us; speedup 1.0000x reference)
//
#include <hip/hip_runtime.h>
#include <math.h>

// SelfCorrectingPointProcess — telescoped form, depth-2 pipelined loads,
// occupancy-capped registers (__launch_bounds__(256,8) -> <=64 VGPR ->
// 32 waves/CU).
//
// out[n] = loglik - comp
// loglik = mu*S1 - beta*S2,  S1 = sum m_i*t_i,  S2 = sum m_i*i
// comp   = [ (1-q)*S + q^Ntot*e^{mu*t1} - e^{mu*t0} ] / mu
//   where q = e^{-beta},  S = sum_i m_i * e^{mu*t_i - beta*exclN_i}
// (telescoping removes the prev_t forward-fill scan and 2 of 3 exps.)
//
// exclN via ballots: mask is {0,1}; 4 __ballot's per 256-elem chunk,
// mbcnt gives below-lane popcount (no serial shuffle scan).

#define T_LEN 2048
#define CHUNK 256  // 64 lanes x float4
#define NCHUNK (T_LEN / CHUNK)

__global__ __launch_bounds__(256, 8) void scpp_kernel(
    const float* __restrict__ event_times,
    const float* __restrict__ input_mask,
    const float* __restrict__ t0p, const float* __restrict__ t1p,
    const float* __restrict__ mup, const float* __restrict__ betap,
    float* __restrict__ out, int n_rows)
{
    const int lane = threadIdx.x & 63;
    const int row  = blockIdx.x * 4 + (threadIdx.x >> 6);
    if (row >= n_rows) return;

    const float t0   = t0p[0];
    const float t1   = t1p[0];
    const float mu   = log1pf(expf(mup[0]));    // softplus
    const float beta = log1pf(expf(betap[0]));  // softplus

    const float* tp = event_times + (size_t)row * T_LEN + lane * 4;
    const float* mp = input_mask  + (size_t)row * T_LEN + lane * 4;

    float carry = 0.f;                 // wave-uniform masked count so far
    float S = 0.f, S1 = 0.f, S2 = 0.f;

    // prime the pipeline
    float4 tv = *(const float4*)tp;
    float4 mv = *(const float4*)mp;

    #pragma unroll
    for (int c = 0; c < NCHUNK; ++c) {
        float4 tvn, mvn;
        if (c + 1 < NCHUNK) {          // issue next chunk's loads early
            tvn = *(const float4*)(tp + (c + 1) * CHUNK);
            mvn = *(const float4*)(mp + (c + 1) * CHUNK);
        }

        const float t[4] = {tv.x, tv.y, tv.z, tv.w};
        const float m[4] = {mv.x, mv.y, mv.z, mv.w};
        const int base = c * CHUNK + lane * 4;

        // exclusive masked count via ballots (no serial scan chain)
        unsigned below_i = 0, tot_i = 0;
        #pragma unroll
        for (int j = 0; j < 4; ++j) {
            const unsigned long long b = __ballot(m[j] > 0.5f);
            below_i += __builtin_amdgcn_mbcnt_hi((unsigned)(b >> 32),
                       __builtin_amdgcn_mbcnt_lo((unsigned)b, 0u));
            tot_i   += (unsigned)__popcll(b);
        }
        const float below = (float)below_i;

        float local = 0.f;
        #pragma unroll
        for (int j = 0; j < 4; ++j) {
            const float exclN = carry + below + local;       // N before elem
            const float arg   = fmaf(mu, t[j], -beta * exclN);
            S  = fmaf(m[j], __expf(arg), S);
            S1 = fmaf(m[j], t[j], S1);
            S2 = fmaf(m[j], (float)(base + j), S2);
            local += m[j];
        }
        carry += (float)tot_i;

        tv = tvn; mv = mvn;
    }

    // butterfly reductions across the wave
    #pragma unroll
    for (int d = 32; d >= 1; d >>= 1) {
        S  += __shfl_xor(S,  d, 64);
        S1 += __shfl_xor(S1, d, 64);
        S2 += __shfl_xor(S2, d, 64);
    }

    if (lane == 0) {
        const float q   = __expf(-beta);
        const float qK  = __expf(-beta * carry);   // carry = total masked count
        const float C   = (1.f - q) * S + qK * __expf(mu * t1) - __expf(mu * t0);
        out[row] = (mu * S1 - beta * S2) - C / mu;
    }
}

extern "C" void kernel_launch(void* const* d_in, const int* in_sizes, int n_in,
                              void* d_out, int out_size, void* d_ws, size_t ws_size,
                              hipStream_t stream) {
    const float* event_times = (const float*)d_in[0];
    // d_in[1] = spatial_locations, unused by the reference
    const float* input_mask  = (const float*)d_in[2];
    const float* t0          = (const float*)d_in[3];
    const float* t1          = (const float*)d_in[4];
    const float* mu_param    = (const float*)d_in[5];
    const float* beta_param  = (const float*)d_in[6];
    float* out = (float*)d_out;

    const int n_rows = in_sizes[0] / T_LEN;  // 8192
    dim3 grid((n_rows + 3) / 4);             // 4 rows (waves) per 256-thread block
    scpp_kernel<<<grid, 256, 0, stream>>>(event_times, input_mask, t0, t1,
                                          mu_param, beta_param, out, n_rows);
}